// Round 8
// baseline (316.856 us; speedup 1.0000x reference)
//
#include <hip/hip_runtime.h>

// VectorQuantizer: z (8,64,8192) f32, codebook (1024,64) f32
// Outputs (concatenated f32): z_q_st [4194304], vq_loss [1], codes [65536]
//
// codes must match numpy fp32 argmin BIT-EXACTLY -> replicate numpy op order:
//   zsq/wsq: pairwise_sum n=64 (8 serial column accumulators, rounded squares)
//   dot:     single serial FMA chain over k ascending (BLAS sgemm order)
//   dist:    fl(fl(zsq - fl(2*dot)) + wsq), argmin = first occurrence of min.
//
// COUNTER ERRATA (R7 post-mortem): FETCH/WRITE_SIZE are KB. There were never
// GB-scale over-fetches; the dist kernel is VALU-ISSUE-bound. Optimization
// target = FMA density per issue slot:
//   - codebook transposed to wT[k][c] -> per k-step the 16-code group's w
//     values are ONE aligned s_load_dwordx16 (uniform address, SGPR dest).
//   - 16 serial FMA chains per ds_read_b32 of z[k] (z in LDS, stride 65 ->
//     2-way bank aliasing, free).
//   - BLK=64, 16.6 KB LDS -> 9 blocks/CU for latency hiding.

#define T_DIM 8192
#define D_DIM 64
#define C_DIM 1024
#define B_DIM 8
#define NROWS (B_DIM * T_DIM)           // 65536 vectors
#define NELEM (B_DIM * D_DIM * T_DIM)   // 4194304 elements
#define SEGS 4
#define CODES_PER_SEG (C_DIM / SEGS)    // 256
#define BLK 64                           // threads per dist block (1 wave)
#define ZSTRIDE 65                       // LDS row stride: 2-way bank alias
#define EPI_BLOCKS (NELEM / 4 / 256)    // 4096 blocks, 1 float4/thread

#define R64(M) M(0) M(1) M(2) M(3) M(4) M(5) M(6) M(7) \
  M(8) M(9) M(10) M(11) M(12) M(13) M(14) M(15) \
  M(16) M(17) M(18) M(19) M(20) M(21) M(22) M(23) \
  M(24) M(25) M(26) M(27) M(28) M(29) M(30) M(31) \
  M(32) M(33) M(34) M(35) M(36) M(37) M(38) M(39) \
  M(40) M(41) M(42) M(43) M(44) M(45) M(46) M(47) \
  M(48) M(49) M(50) M(51) M(52) M(53) M(54) M(55) \
  M(56) M(57) M(58) M(59) M(60) M(61) M(62) M(63)

#define SQ_(x) __fmul_rn(x, x)
#define AD_(a, b) __fadd_rn(a, b)

// numpy pairwise_sum of 64 pre-rounded squares of scalars p0..p63 -> dst.
#define PAIRWISE64(p, dst) \
  float pr0 = SQ_(p##0);  pr0 = AD_(pr0, SQ_(p##8));  pr0 = AD_(pr0, SQ_(p##16)); pr0 = AD_(pr0, SQ_(p##24)); pr0 = AD_(pr0, SQ_(p##32)); pr0 = AD_(pr0, SQ_(p##40)); pr0 = AD_(pr0, SQ_(p##48)); pr0 = AD_(pr0, SQ_(p##56)); \
  float pr1 = SQ_(p##1);  pr1 = AD_(pr1, SQ_(p##9));  pr1 = AD_(pr1, SQ_(p##17)); pr1 = AD_(pr1, SQ_(p##25)); pr1 = AD_(pr1, SQ_(p##33)); pr1 = AD_(pr1, SQ_(p##41)); pr1 = AD_(pr1, SQ_(p##49)); pr1 = AD_(pr1, SQ_(p##57)); \
  float pr2 = SQ_(p##2);  pr2 = AD_(pr2, SQ_(p##10)); pr2 = AD_(pr2, SQ_(p##18)); pr2 = AD_(pr2, SQ_(p##26)); pr2 = AD_(pr2, SQ_(p##34)); pr2 = AD_(pr2, SQ_(p##42)); pr2 = AD_(pr2, SQ_(p##50)); pr2 = AD_(pr2, SQ_(p##58)); \
  float pr3 = SQ_(p##3);  pr3 = AD_(pr3, SQ_(p##11)); pr3 = AD_(pr3, SQ_(p##19)); pr3 = AD_(pr3, SQ_(p##27)); pr3 = AD_(pr3, SQ_(p##35)); pr3 = AD_(pr3, SQ_(p##43)); pr3 = AD_(pr3, SQ_(p##51)); pr3 = AD_(pr3, SQ_(p##59)); \
  float pr4 = SQ_(p##4);  pr4 = AD_(pr4, SQ_(p##12)); pr4 = AD_(pr4, SQ_(p##20)); pr4 = AD_(pr4, SQ_(p##28)); pr4 = AD_(pr4, SQ_(p##36)); pr4 = AD_(pr4, SQ_(p##44)); pr4 = AD_(pr4, SQ_(p##52)); pr4 = AD_(pr4, SQ_(p##60)); \
  float pr5 = SQ_(p##5);  pr5 = AD_(pr5, SQ_(p##13)); pr5 = AD_(pr5, SQ_(p##21)); pr5 = AD_(pr5, SQ_(p##29)); pr5 = AD_(pr5, SQ_(p##37)); pr5 = AD_(pr5, SQ_(p##45)); pr5 = AD_(pr5, SQ_(p##53)); pr5 = AD_(pr5, SQ_(p##61)); \
  float pr6 = SQ_(p##6);  pr6 = AD_(pr6, SQ_(p##14)); pr6 = AD_(pr6, SQ_(p##22)); pr6 = AD_(pr6, SQ_(p##30)); pr6 = AD_(pr6, SQ_(p##38)); pr6 = AD_(pr6, SQ_(p##46)); pr6 = AD_(pr6, SQ_(p##54)); pr6 = AD_(pr6, SQ_(p##62)); \
  float pr7 = SQ_(p##7);  pr7 = AD_(pr7, SQ_(p##15)); pr7 = AD_(pr7, SQ_(p##23)); pr7 = AD_(pr7, SQ_(p##31)); pr7 = AD_(pr7, SQ_(p##39)); pr7 = AD_(pr7, SQ_(p##47)); pr7 = AD_(pr7, SQ_(p##55)); pr7 = AD_(pr7, SQ_(p##63)); \
  float dst = AD_(AD_(AD_(pr0, pr1), AD_(pr2, pr3)), AD_(AD_(pr4, pr5), AD_(pr6, pr7)));

// Prep: wsq[c] (numpy pairwise order) and transposed codebook wT[k*1024+c].
__global__ void vq_prep_kernel(const float* __restrict__ cb,
                               float* __restrict__ wT,
                               float* __restrict__ wsq) {
    int c = blockIdx.x * 64 + threadIdx.x;   // 0..1023
    const float* wp = cb + ((size_t)c << 6);
#define LOADW(k) float w##k = wp[k];
    R64(LOADW)
#undef LOADW
    PAIRWISE64(w, s)
    wsq[c] = s;
#define STOREW(k) wT[((size_t)k << 10) + c] = w##k;
    R64(STOREW)
#undef STOREW
}

// One thread per row; blockIdx.y = 256-code segment. z row staged in LDS
// (stride 65 -> free 2-way alias). Inner loop: 16 codes in flight; per k:
// 1 ds_read_b32 (z[k]) + 1 s_load_dwordx16 (wT[k][cc..cc+15], uniform) +
// 16 fmaf. Serial chain over k ascending per code = sgemm accum order.
__global__ __launch_bounds__(BLK)
void vq_dist_kernel(const float* __restrict__ z,
                    const float* __restrict__ wT,
                    const float* __restrict__ wsq,
                    float2* __restrict__ pairs) {
    __shared__ float z_lds[BLK * ZSTRIDE];   // 16.6 KB

    const int tid = threadIdx.x;
    const int row = blockIdx.x * BLK + tid;           // 0..65535
    const int seg = blockIdx.y;                       // 0..3 (uniform)
    const int c0 = seg * CODES_PER_SEG;
    const int b = row >> 13;                          // row / 8192
    const int t = row & (T_DIM - 1);

    // --- stage z row into LDS; zsq in numpy pairwise order ---
    // z[b, d, t]: stride T_DIM along d; lanes t-consecutive -> coalesced
    const float* zp = z + (size_t)b * (D_DIM * T_DIM) + t;
    float col[8];
#pragma unroll
    for (int d = 0; d < 8; ++d) {
        float v = zp[(size_t)d * T_DIM];
        z_lds[tid * ZSTRIDE + d] = v;
        col[d] = __fmul_rn(v, v);
    }
#pragma unroll
    for (int d = 8; d < 64; ++d) {
        float v = zp[(size_t)d * T_DIM];
        z_lds[tid * ZSTRIDE + d] = v;
        col[d & 7] = __fadd_rn(col[d & 7], __fmul_rn(v, v));
    }
    const float zsq = __fadd_rn(
        __fadd_rn(__fadd_rn(col[0], col[1]), __fadd_rn(col[2], col[3])),
        __fadd_rn(__fadd_rn(col[4], col[5]), __fadd_rn(col[6], col[7])));
    __syncthreads();

    const float* zbase = z_lds + tid * ZSTRIDE;
    float bestd = 3.4e38f;
    int besti = 0;
#pragma unroll 1
    for (int cc = 0; cc < CODES_PER_SEG; cc += 16) {
        // Opaque zero offset: blocks LICM from hoisting the 64 loop-invariant
        // ds_reads into 64 live VGPRs (the R3-R6 allocator-war trigger).
        int zoff;
        asm volatile("s_mov_b32 %0, 0" : "=s"(zoff));
        const float* zlo = zbase + zoff;

        const float* wg = wT + (c0 + cc);   // uniform; wg + k*1024 is 64B-aligned
        float a0 = 0.f, a1 = 0.f, a2 = 0.f, a3 = 0.f;
        float a4 = 0.f, a5 = 0.f, a6 = 0.f, a7 = 0.f;
        float a8 = 0.f, a9 = 0.f, a10 = 0.f, a11 = 0.f;
        float a12 = 0.f, a13 = 0.f, a14 = 0.f, a15 = 0.f;
#define STEP(k) { float zv = zlo[k]; const float* wk = wg + ((size_t)(k) << 10); \
        a0 = fmaf(zv, wk[0], a0);   a1 = fmaf(zv, wk[1], a1); \
        a2 = fmaf(zv, wk[2], a2);   a3 = fmaf(zv, wk[3], a3); \
        a4 = fmaf(zv, wk[4], a4);   a5 = fmaf(zv, wk[5], a5); \
        a6 = fmaf(zv, wk[6], a6);   a7 = fmaf(zv, wk[7], a7); \
        a8 = fmaf(zv, wk[8], a8);   a9 = fmaf(zv, wk[9], a9); \
        a10 = fmaf(zv, wk[10], a10); a11 = fmaf(zv, wk[11], a11); \
        a12 = fmaf(zv, wk[12], a12); a13 = fmaf(zv, wk[13], a13); \
        a14 = fmaf(zv, wk[14], a14); a15 = fmaf(zv, wk[15], a15); }
        R64(STEP)
#undef STEP
        // d = (zsq - 2*dot) + wsq, each op individually rounded; ascending
        // code order + strict < => numpy first-min semantics.
        const float* wq = wsq + (c0 + cc);  // uniform -> s_load
#define FIN(j) { float dj = __fadd_rn(__fsub_rn(zsq, __fmul_rn(2.0f, a##j)), wq[j]); \
                 if (dj < bestd) { bestd = dj; besti = c0 + cc + j; } }
        FIN(0) FIN(1) FIN(2) FIN(3) FIN(4) FIN(5) FIN(6) FIN(7)
        FIN(8) FIN(9) FIN(10) FIN(11) FIN(12) FIN(13) FIN(14) FIN(15)
#undef FIN
    }
    pairs[seg * NROWS + row] = make_float2(bestd, (float)besti);
}

__global__ void vq_argmin_kernel(const float2* __restrict__ pairs,
                                 float* __restrict__ codes) {
    int row = blockIdx.x * blockDim.x + threadIdx.x;
    float2 best = pairs[row];
#pragma unroll
    for (int s = 1; s < SEGS; ++s) {
        float2 p = pairs[s * NROWS + row];
        if (p.x < best.x) best = p;  // ascending seg order, strict <
    }
    codes[row] = best.y;
}

// One float4 (4 consecutive t) per thread; per-block double partial to ws.
__global__ void vq_epilogue_kernel(const float* __restrict__ z,
                                   const float* __restrict__ cb,
                                   const float* __restrict__ codes,
                                   float* __restrict__ out,
                                   double* __restrict__ partials) {
    const int q = blockIdx.x * 256 + threadIdx.x;  // quad index, 0..1048575
    const int i = q << 2;                          // element index
    const int t = i & (T_DIM - 1);                 // multiple of 4
    const int bd = i >> 13;
    const int d = bd & (D_DIM - 1);                // uniform within a wave
    const int b = bd >> 6;
    const int row = (b << 13) | t;

    float4 cr = *(const float4*)(codes + row);     // 4 consecutive codes
    float4 zv = *(const float4*)(z + i);
    float w0 = cb[((int)cr.x << 6) + d];           // gathers, 256 KiB table
    float w1 = cb[((int)cr.y << 6) + d];
    float w2 = cb[((int)cr.z << 6) + d];
    float w3 = cb[((int)cr.w << 6) + d];

    float4 df = make_float4(w0 - zv.x, w1 - zv.y, w2 - zv.z, w3 - zv.w);
    float4 o = make_float4(zv.x + df.x, zv.y + df.y, zv.z + df.z, zv.w + df.w);
    *(float4*)(out + i) = o;                       // z + (z_q - z), ref order

    double v = (double)df.x * df.x + (double)df.y * df.y +
               (double)df.z * df.z + (double)df.w * df.w;
#pragma unroll
    for (int o2 = 32; o2 > 0; o2 >>= 1) v += __shfl_down(v, o2, 64);

    __shared__ double red[4];
    if ((threadIdx.x & 63) == 0) red[threadIdx.x >> 6] = v;
    __syncthreads();
    if (threadIdx.x == 0)
        partials[blockIdx.x] = ((red[0] + red[1]) + (red[2] + red[3]));
}

__global__ void vq_loss_kernel(const double* __restrict__ partials,
                               float* __restrict__ out_loss) {
    double s = 0.0;
    for (int i = threadIdx.x; i < EPI_BLOCKS; i += 256) s += partials[i];
#pragma unroll
    for (int o = 32; o > 0; o >>= 1) s += __shfl_down(s, o, 64);
    __shared__ double red[4];
    if ((threadIdx.x & 63) == 0) red[threadIdx.x >> 6] = s;
    __syncthreads();
    if (threadIdx.x == 0) {
        double tot = (red[0] + red[1]) + (red[2] + red[3]);
        // vq_loss = codebook_loss + 0.25*commitment_loss = 1.25*mean(diff^2)
        out_loss[0] = (float)(1.25 * tot / (double)NELEM);
    }
}

extern "C" void kernel_launch(void* const* d_in, const int* in_sizes, int n_in,
                              void* d_out, int out_size, void* d_ws, size_t ws_size,
                              hipStream_t stream) {
    const float* z  = (const float*)d_in[0];   // 4194304
    const float* cb = (const float*)d_in[1];   // 65536

    float* out      = (float*)d_out;
    float* out_loss = out + NELEM;             // index 4194304
    float* codes    = out + NELEM + 1;         // 65536 floats

    char* ws = (char*)d_ws;
    float* wT        = (float*)ws;                      // 256 KiB [k][c]
    float* wsq       = (float*)(ws + 262144);           // 4 KiB
    double* partials = (double*)(ws + 262144 + 4096);   // 32 KiB
    float2* pairs    = (float2*)(ws + 262144 + 4096 + 32768);  // 2 MiB

    vq_prep_kernel<<<C_DIM / 64, 64, 0, stream>>>(cb, wT, wsq);

    dim3 grid1(NROWS / BLK, SEGS);
    vq_dist_kernel<<<grid1, BLK, 0, stream>>>(z, wT, wsq, pairs);

    vq_argmin_kernel<<<NROWS / 256, 256, 0, stream>>>(pairs, codes);

    vq_epilogue_kernel<<<EPI_BLOCKS, 256, 0, stream>>>(z, cb, codes, out, partials);

    vq_loss_kernel<<<1, 256, 0, stream>>>(partials, out_loss);
}

// Round 9
// 279.387 us; speedup vs baseline: 1.1341x; 1.1341x over previous
//
#include <hip/hip_runtime.h>

// VectorQuantizer: z (8,64,8192) f32, codebook (1024,64) f32
// Outputs (concatenated f32): z_q_st [4194304], vq_loss [1], codes [65536]
//
// codes must match numpy fp32 argmin BIT-EXACTLY. Constraint: each distance's
// dot must be ONE serial ascending-k fp32 fmaf chain (BLAS order), and
// d = fl(fl(zsq - fl(2*dot)) + wsq) with numpy-pairwise zsq/wsq. This does
// NOT forbid tiling over outputs -> register-tiled outer-product GEMM:
// thread = 4 rows x 8 codes (32 serial chains), per k: 1 float4 z-load
// (4 consecutive t) + 2 float4 wT-loads (transposed codebook) + 32 fmaf.
// 91% FMA density, ~55 VGPR live set -> no allocator war (R2-R8 lesson:
// keeping 64 z in VGPRs per thread is unwinnable; 4-at-a-time streams).

#define T_DIM 8192
#define D_DIM 64
#define C_DIM 1024
#define B_DIM 8
#define NROWS (B_DIM * T_DIM)           // 65536 vectors
#define NELEM (B_DIM * D_DIM * T_DIM)   // 4194304 elements
#define SEGS 8                           // code-blocks of 128
#define EPI_BLOCKS (NELEM / 4 / 256)    // 4096 blocks, 1 float4/thread

#define R64(M) M(0) M(1) M(2) M(3) M(4) M(5) M(6) M(7) \
  M(8) M(9) M(10) M(11) M(12) M(13) M(14) M(15) \
  M(16) M(17) M(18) M(19) M(20) M(21) M(22) M(23) \
  M(24) M(25) M(26) M(27) M(28) M(29) M(30) M(31) \
  M(32) M(33) M(34) M(35) M(36) M(37) M(38) M(39) \
  M(40) M(41) M(42) M(43) M(44) M(45) M(46) M(47) \
  M(48) M(49) M(50) M(51) M(52) M(53) M(54) M(55) \
  M(56) M(57) M(58) M(59) M(60) M(61) M(62) M(63)

#define SQ_(x) __fmul_rn(x, x)
#define AD_(a, b) __fadd_rn(a, b)

// numpy pairwise_sum of 64 pre-rounded squares of scalars p0..p63 -> dst.
#define PAIRWISE64(p, dst) \
  float pr0 = SQ_(p##0);  pr0 = AD_(pr0, SQ_(p##8));  pr0 = AD_(pr0, SQ_(p##16)); pr0 = AD_(pr0, SQ_(p##24)); pr0 = AD_(pr0, SQ_(p##32)); pr0 = AD_(pr0, SQ_(p##40)); pr0 = AD_(pr0, SQ_(p##48)); pr0 = AD_(pr0, SQ_(p##56)); \
  float pr1 = SQ_(p##1);  pr1 = AD_(pr1, SQ_(p##9));  pr1 = AD_(pr1, SQ_(p##17)); pr1 = AD_(pr1, SQ_(p##25)); pr1 = AD_(pr1, SQ_(p##33)); pr1 = AD_(pr1, SQ_(p##41)); pr1 = AD_(pr1, SQ_(p##49)); pr1 = AD_(pr1, SQ_(p##57)); \
  float pr2 = SQ_(p##2);  pr2 = AD_(pr2, SQ_(p##10)); pr2 = AD_(pr2, SQ_(p##18)); pr2 = AD_(pr2, SQ_(p##26)); pr2 = AD_(pr2, SQ_(p##34)); pr2 = AD_(pr2, SQ_(p##42)); pr2 = AD_(pr2, SQ_(p##50)); pr2 = AD_(pr2, SQ_(p##58)); \
  float pr3 = SQ_(p##3);  pr3 = AD_(pr3, SQ_(p##11)); pr3 = AD_(pr3, SQ_(p##19)); pr3 = AD_(pr3, SQ_(p##27)); pr3 = AD_(pr3, SQ_(p##35)); pr3 = AD_(pr3, SQ_(p##43)); pr3 = AD_(pr3, SQ_(p##51)); pr3 = AD_(pr3, SQ_(p##59)); \
  float pr4 = SQ_(p##4);  pr4 = AD_(pr4, SQ_(p##12)); pr4 = AD_(pr4, SQ_(p##20)); pr4 = AD_(pr4, SQ_(p##28)); pr4 = AD_(pr4, SQ_(p##36)); pr4 = AD_(pr4, SQ_(p##44)); pr4 = AD_(pr4, SQ_(p##52)); pr4 = AD_(pr4, SQ_(p##60)); \
  float pr5 = SQ_(p##5);  pr5 = AD_(pr5, SQ_(p##13)); pr5 = AD_(pr5, SQ_(p##21)); pr5 = AD_(pr5, SQ_(p##29)); pr5 = AD_(pr5, SQ_(p##37)); pr5 = AD_(pr5, SQ_(p##45)); pr5 = AD_(pr5, SQ_(p##53)); pr5 = AD_(pr5, SQ_(p##61)); \
  float pr6 = SQ_(p##6);  pr6 = AD_(pr6, SQ_(p##14)); pr6 = AD_(pr6, SQ_(p##22)); pr6 = AD_(pr6, SQ_(p##30)); pr6 = AD_(pr6, SQ_(p##38)); pr6 = AD_(pr6, SQ_(p##46)); pr6 = AD_(pr6, SQ_(p##54)); pr6 = AD_(pr6, SQ_(p##62)); \
  float pr7 = SQ_(p##7);  pr7 = AD_(pr7, SQ_(p##15)); pr7 = AD_(pr7, SQ_(p##23)); pr7 = AD_(pr7, SQ_(p##31)); pr7 = AD_(pr7, SQ_(p##39)); pr7 = AD_(pr7, SQ_(p##47)); pr7 = AD_(pr7, SQ_(p##55)); pr7 = AD_(pr7, SQ_(p##63)); \
  float dst = AD_(AD_(AD_(pr0, pr1), AD_(pr2, pr3)), AD_(AD_(pr4, pr5), AD_(pr6, pr7)));

// Prep: wsq[c] (numpy pairwise order) and transposed codebook wT[k*1024+c].
__global__ void vq_prep_kernel(const float* __restrict__ cb,
                               float* __restrict__ wT,
                               float* __restrict__ wsq) {
    int c = blockIdx.x * 64 + threadIdx.x;   // 0..1023
    const float* wp = cb + ((size_t)c << 6);
#define LOADW(k) float w##k = wp[k];
    R64(LOADW)
#undef LOADW
    PAIRWISE64(w, s)
    wsq[c] = s;
#define STOREW(k) wT[((size_t)k << 10) + c] = w##k;
    R64(STOREW)
#undef STOREW
}

// ||z_row||^2 in numpy pairwise order; one thread per row, streaming loads.
__global__ void vq_zsq_kernel(const float* __restrict__ z,
                              float* __restrict__ zsq) {
    int row = blockIdx.x * 256 + threadIdx.x;
    int b = row >> 13, t = row & (T_DIM - 1);
    const float* zp = z + (size_t)b * (D_DIM * T_DIM) + t;
    float col[8];
#pragma unroll
    for (int d = 0; d < 8; ++d) {
        float v = zp[(size_t)d * T_DIM];
        col[d] = __fmul_rn(v, v);
    }
#pragma unroll
    for (int d = 8; d < 64; ++d) {
        float v = zp[(size_t)d * T_DIM];
        col[d & 7] = __fadd_rn(col[d & 7], __fmul_rn(v, v));
    }
    zsq[row] = __fadd_rn(
        __fadd_rn(__fadd_rn(col[0], col[1]), __fadd_rn(col[2], col[3])),
        __fadd_rn(__fadd_rn(col[4], col[5]), __fadd_rn(col[6], col[7])));
}

// Register-tiled GEMM: block = 64 rows x 128 codes, thread = 4 rows x 8 codes.
// acc[r][c] is a single serial ascending-k fmaf chain (= BLAS/numpy order).
__global__ __launch_bounds__(256)
void vq_gemm_kernel(const float* __restrict__ z,
                    const float* __restrict__ wT,
                    const float* __restrict__ zsq,
                    const float* __restrict__ wsq,
                    float2* __restrict__ pairs) {
    const int tid = threadIdx.x;
    const int rq = tid & 15;                  // row-quad 0..15
    const int cq = tid >> 4;                  // code-oct 0..15
    const int row0 = blockIdx.x * 64 + rq * 4;      // first of 4 rows
    const int code0 = blockIdx.y * 128 + cq * 8;    // first of 8 codes
    const int b = row0 >> 13;
    const int t = row0 & (T_DIM - 1);               // multiple of 4

    const float* zp = z + (size_t)b * (D_DIM * T_DIM) + t;  // + k*8192
    const float* wp = wT + code0;                           // + k*1024

    float acc[4][8];
#pragma unroll
    for (int r = 0; r < 4; ++r)
#pragma unroll
        for (int c = 0; c < 8; ++c) acc[r][c] = 0.0f;

#pragma unroll
    for (int k = 0; k < D_DIM; ++k) {
        const float4 z4 = *(const float4*)(zp + (size_t)k * T_DIM);
        const float4 wa = *(const float4*)(wp + (size_t)k * C_DIM);
        const float4 wb = *(const float4*)(wp + (size_t)k * C_DIM + 4);
        const float zr[4] = {z4.x, z4.y, z4.z, z4.w};
        const float wc[8] = {wa.x, wa.y, wa.z, wa.w, wb.x, wb.y, wb.z, wb.w};
#pragma unroll
        for (int r = 0; r < 4; ++r)
#pragma unroll
            for (int c = 0; c < 8; ++c)
                acc[r][c] = fmaf(zr[r], wc[c], acc[r][c]);  // serial in k
    }

    const float4 zs4 = *(const float4*)(zsq + row0);
    const float4 wsa = *(const float4*)(wsq + code0);
    const float4 wsb = *(const float4*)(wsq + code0 + 4);
    const float zs[4] = {zs4.x, zs4.y, zs4.z, zs4.w};
    const float wsv[8] = {wsa.x, wsa.y, wsa.z, wsa.w,
                          wsb.x, wsb.y, wsb.z, wsb.w};

    // Per-thread first-min over 8 codes (ascending c, strict <), per row.
    __shared__ float2 red[16 * 64];   // [code-oct][local row], 8 KiB
#pragma unroll
    for (int r = 0; r < 4; ++r) {
        float bestd = 3.4e38f;
        int besti = 0;
#pragma unroll
        for (int c = 0; c < 8; ++c) {
            // d = (zsq - 2*dot) + wsq, each op individually rounded
            float d = __fadd_rn(__fsub_rn(zs[r], __fmul_rn(2.0f, acc[r][c])),
                                wsv[c]);
            if (d < bestd) { bestd = d; besti = code0 + c; }
        }
        red[cq * 64 + rq * 4 + r] = make_float2(bestd, (float)besti);
    }
    __syncthreads();

    // First wave reduces over the 16 code-octs (ascending -> first-min).
    if (tid < 64) {
        float2 best = red[tid];
#pragma unroll
        for (int c = 1; c < 16; ++c) {
            float2 p = red[c * 64 + tid];
            if (p.x < best.x) best = p;
        }
        pairs[blockIdx.y * NROWS + blockIdx.x * 64 + tid] = best;
    }
}

__global__ void vq_argmin_kernel(const float2* __restrict__ pairs,
                                 float* __restrict__ codes) {
    int row = blockIdx.x * blockDim.x + threadIdx.x;
    float2 best = pairs[row];
#pragma unroll
    for (int s = 1; s < SEGS; ++s) {
        float2 p = pairs[s * NROWS + row];
        if (p.x < best.x) best = p;  // ascending seg order, strict <
    }
    codes[row] = best.y;
}

// One float4 (4 consecutive t) per thread; per-block double partial to ws.
__global__ void vq_epilogue_kernel(const float* __restrict__ z,
                                   const float* __restrict__ cb,
                                   const float* __restrict__ codes,
                                   float* __restrict__ out,
                                   double* __restrict__ partials) {
    const int q = blockIdx.x * 256 + threadIdx.x;  // quad index, 0..1048575
    const int i = q << 2;                          // element index
    const int t = i & (T_DIM - 1);                 // multiple of 4
    const int bd = i >> 13;
    const int d = bd & (D_DIM - 1);                // uniform within a wave
    const int b = bd >> 6;
    const int row = (b << 13) | t;

    float4 cr = *(const float4*)(codes + row);     // 4 consecutive codes
    float4 zv = *(const float4*)(z + i);
    float w0 = cb[((int)cr.x << 6) + d];           // gathers, 256 KiB table
    float w1 = cb[((int)cr.y << 6) + d];
    float w2 = cb[((int)cr.z << 6) + d];
    float w3 = cb[((int)cr.w << 6) + d];

    float4 df = make_float4(w0 - zv.x, w1 - zv.y, w2 - zv.z, w3 - zv.w);
    float4 o = make_float4(zv.x + df.x, zv.y + df.y, zv.z + df.z, zv.w + df.w);
    *(float4*)(out + i) = o;                       // z + (z_q - z), ref order

    double v = (double)df.x * df.x + (double)df.y * df.y +
               (double)df.z * df.z + (double)df.w * df.w;
#pragma unroll
    for (int o2 = 32; o2 > 0; o2 >>= 1) v += __shfl_down(v, o2, 64);

    __shared__ double red[4];
    if ((threadIdx.x & 63) == 0) red[threadIdx.x >> 6] = v;
    __syncthreads();
    if (threadIdx.x == 0)
        partials[blockIdx.x] = ((red[0] + red[1]) + (red[2] + red[3]));
}

__global__ void vq_loss_kernel(const double* __restrict__ partials,
                               float* __restrict__ out_loss) {
    double s = 0.0;
    for (int i = threadIdx.x; i < EPI_BLOCKS; i += 256) s += partials[i];
#pragma unroll
    for (int o = 32; o > 0; o >>= 1) s += __shfl_down(s, o, 64);
    __shared__ double red[4];
    if ((threadIdx.x & 63) == 0) red[threadIdx.x >> 6] = s;
    __syncthreads();
    if (threadIdx.x == 0) {
        double tot = (red[0] + red[1]) + (red[2] + red[3]);
        // vq_loss = codebook_loss + 0.25*commitment_loss = 1.25*mean(diff^2)
        out_loss[0] = (float)(1.25 * tot / (double)NELEM);
    }
}

extern "C" void kernel_launch(void* const* d_in, const int* in_sizes, int n_in,
                              void* d_out, int out_size, void* d_ws, size_t ws_size,
                              hipStream_t stream) {
    const float* z  = (const float*)d_in[0];   // 4194304
    const float* cb = (const float*)d_in[1];   // 65536

    float* out      = (float*)d_out;
    float* out_loss = out + NELEM;             // index 4194304
    float* codes    = out + NELEM + 1;         // 65536 floats

    char* ws = (char*)d_ws;
    float* wT        = (float*)ws;                        // 256 KiB [k][c]
    float* wsq       = (float*)(ws + 262144);             // 4 KiB
    float* zsq       = (float*)(ws + 262144 + 4096);      // 256 KiB
    double* partials = (double*)(ws + 524288 + 4096);     // 32 KiB
    float2* pairs    = (float2*)(ws + 524288 + 4096 + 32768);  // 4 MiB

    vq_prep_kernel<<<C_DIM / 64, 64, 0, stream>>>(cb, wT, wsq);

    vq_zsq_kernel<<<NROWS / 256, 256, 0, stream>>>(z, zsq);

    dim3 grid1(NROWS / 64, SEGS);
    vq_gemm_kernel<<<grid1, 256, 0, stream>>>(z, wT, zsq, wsq, pairs);

    vq_argmin_kernel<<<NROWS / 256, 256, 0, stream>>>(pairs, codes);

    vq_epilogue_kernel<<<EPI_BLOCKS, 256, 0, stream>>>(z, cb, codes, out, partials);

    vq_loss_kernel<<<1, 256, 0, stream>>>(partials, out_loss);
}

// Round 10
// 276.496 us; speedup vs baseline: 1.1460x; 1.0105x over previous
//
#include <hip/hip_runtime.h>

// VectorQuantizer: z (8,64,8192) f32, codebook (1024,64) f32
// Outputs (concatenated f32): z_q_st [4194304], vq_loss [1], codes [65536]
//
// codes must match numpy fp32 argmin BIT-EXACTLY. Each distance's dot is ONE
// serial ascending-k fp32 fmaf chain (BLAS order); d = fl(fl(zsq - fl(2*dot))
// + wsq) with numpy-pairwise zsq/wsq; argmin = first occurrence of min.
// Register-tiled GEMM: thread = 4 rows x 8 codes = 32 serial chains.
//
// R9 lesson (the allocator-war, final form): with only 8 KB LDS the backend
// targets 8 waves/EU -> 64-reg budget -> accumulators pushed into AGPRs with
// v_accvgpr shuffles on every fmaf (VALU issue 2.6x the FMA floor). The VGPR
// grant empirically tracks LDS pressure (R7: 34KB->88 regs; R8: 17KB->68;
// R9: 8KB->32). Fix: pad the reduction buffer to 36 KB -> 4 blocks/CU ->
// 4 waves/EU target -> 128-reg budget -> accs live in arch VGPRs.

#define T_DIM 8192
#define D_DIM 64
#define C_DIM 1024
#define B_DIM 8
#define NROWS (B_DIM * T_DIM)           // 65536 vectors
#define NELEM (B_DIM * D_DIM * T_DIM)   // 4194304 elements
#define SEGS 8                           // code-blocks of 128
#define RSTRIDE 288                      // red row stride -> 36,864 B LDS
#define EPI_BLOCKS (NELEM / 4 / 256)    // 4096 blocks, 1 float4/thread

#define R64(M) M(0) M(1) M(2) M(3) M(4) M(5) M(6) M(7) \
  M(8) M(9) M(10) M(11) M(12) M(13) M(14) M(15) \
  M(16) M(17) M(18) M(19) M(20) M(21) M(22) M(23) \
  M(24) M(25) M(26) M(27) M(28) M(29) M(30) M(31) \
  M(32) M(33) M(34) M(35) M(36) M(37) M(38) M(39) \
  M(40) M(41) M(42) M(43) M(44) M(45) M(46) M(47) \
  M(48) M(49) M(50) M(51) M(52) M(53) M(54) M(55) \
  M(56) M(57) M(58) M(59) M(60) M(61) M(62) M(63)

#define SQ_(x) __fmul_rn(x, x)
#define AD_(a, b) __fadd_rn(a, b)

// numpy pairwise_sum of 64 pre-rounded squares of scalars p0..p63 -> dst.
#define PAIRWISE64(p, dst) \
  float pr0 = SQ_(p##0);  pr0 = AD_(pr0, SQ_(p##8));  pr0 = AD_(pr0, SQ_(p##16)); pr0 = AD_(pr0, SQ_(p##24)); pr0 = AD_(pr0, SQ_(p##32)); pr0 = AD_(pr0, SQ_(p##40)); pr0 = AD_(pr0, SQ_(p##48)); pr0 = AD_(pr0, SQ_(p##56)); \
  float pr1 = SQ_(p##1);  pr1 = AD_(pr1, SQ_(p##9));  pr1 = AD_(pr1, SQ_(p##17)); pr1 = AD_(pr1, SQ_(p##25)); pr1 = AD_(pr1, SQ_(p##33)); pr1 = AD_(pr1, SQ_(p##41)); pr1 = AD_(pr1, SQ_(p##49)); pr1 = AD_(pr1, SQ_(p##57)); \
  float pr2 = SQ_(p##2);  pr2 = AD_(pr2, SQ_(p##10)); pr2 = AD_(pr2, SQ_(p##18)); pr2 = AD_(pr2, SQ_(p##26)); pr2 = AD_(pr2, SQ_(p##34)); pr2 = AD_(pr2, SQ_(p##42)); pr2 = AD_(pr2, SQ_(p##50)); pr2 = AD_(pr2, SQ_(p##58)); \
  float pr3 = SQ_(p##3);  pr3 = AD_(pr3, SQ_(p##11)); pr3 = AD_(pr3, SQ_(p##19)); pr3 = AD_(pr3, SQ_(p##27)); pr3 = AD_(pr3, SQ_(p##35)); pr3 = AD_(pr3, SQ_(p##43)); pr3 = AD_(pr3, SQ_(p##51)); pr3 = AD_(pr3, SQ_(p##59)); \
  float pr4 = SQ_(p##4);  pr4 = AD_(pr4, SQ_(p##12)); pr4 = AD_(pr4, SQ_(p##20)); pr4 = AD_(pr4, SQ_(p##28)); pr4 = AD_(pr4, SQ_(p##36)); pr4 = AD_(pr4, SQ_(p##44)); pr4 = AD_(pr4, SQ_(p##52)); pr4 = AD_(pr4, SQ_(p##60)); \
  float pr5 = SQ_(p##5);  pr5 = AD_(pr5, SQ_(p##13)); pr5 = AD_(pr5, SQ_(p##21)); pr5 = AD_(pr5, SQ_(p##29)); pr5 = AD_(pr5, SQ_(p##37)); pr5 = AD_(pr5, SQ_(p##45)); pr5 = AD_(pr5, SQ_(p##53)); pr5 = AD_(pr5, SQ_(p##61)); \
  float pr6 = SQ_(p##6);  pr6 = AD_(pr6, SQ_(p##14)); pr6 = AD_(pr6, SQ_(p##22)); pr6 = AD_(pr6, SQ_(p##30)); pr6 = AD_(pr6, SQ_(p##38)); pr6 = AD_(pr6, SQ_(p##46)); pr6 = AD_(pr6, SQ_(p##54)); pr6 = AD_(pr6, SQ_(p##62)); \
  float pr7 = SQ_(p##7);  pr7 = AD_(pr7, SQ_(p##15)); pr7 = AD_(pr7, SQ_(p##23)); pr7 = AD_(pr7, SQ_(p##31)); pr7 = AD_(pr7, SQ_(p##39)); pr7 = AD_(pr7, SQ_(p##47)); pr7 = AD_(pr7, SQ_(p##55)); pr7 = AD_(pr7, SQ_(p##63)); \
  float dst = AD_(AD_(AD_(pr0, pr1), AD_(pr2, pr3)), AD_(AD_(pr4, pr5), AD_(pr6, pr7)));

// Prep: wsq[c] (numpy pairwise order) and transposed codebook wT[k*1024+c].
__global__ void vq_prep_kernel(const float* __restrict__ cb,
                               float* __restrict__ wT,
                               float* __restrict__ wsq) {
    int c = blockIdx.x * 64 + threadIdx.x;   // 0..1023
    const float* wp = cb + ((size_t)c << 6);
#define LOADW(k) float w##k = wp[k];
    R64(LOADW)
#undef LOADW
    PAIRWISE64(w, s)
    wsq[c] = s;
#define STOREW(k) wT[((size_t)k << 10) + c] = w##k;
    R64(STOREW)
#undef STOREW
}

// ||z_row||^2 in numpy pairwise order; one thread per row, streaming loads.
__global__ void vq_zsq_kernel(const float* __restrict__ z,
                              float* __restrict__ zsq) {
    int row = blockIdx.x * 256 + threadIdx.x;
    int b = row >> 13, t = row & (T_DIM - 1);
    const float* zp = z + (size_t)b * (D_DIM * T_DIM) + t;
    float col[8];
#pragma unroll
    for (int d = 0; d < 8; ++d) {
        float v = zp[(size_t)d * T_DIM];
        col[d] = __fmul_rn(v, v);
    }
#pragma unroll
    for (int d = 8; d < 64; ++d) {
        float v = zp[(size_t)d * T_DIM];
        col[d & 7] = __fadd_rn(col[d & 7], __fmul_rn(v, v));
    }
    zsq[row] = __fadd_rn(
        __fadd_rn(__fadd_rn(col[0], col[1]), __fadd_rn(col[2], col[3])),
        __fadd_rn(__fadd_rn(col[4], col[5]), __fadd_rn(col[6], col[7])));
}

// Register-tiled GEMM: block = 64 rows x 128 codes, thread = 4 rows x 8 codes.
// acc[r][c] is a single serial ascending-k fmaf chain (= BLAS/numpy order).
__global__ __launch_bounds__(256)
void vq_gemm_kernel(const float* __restrict__ z,
                    const float* __restrict__ wT,
                    const float* __restrict__ zsq,
                    const float* __restrict__ wsq,
                    float2* __restrict__ pairs) {
    const int tid = threadIdx.x;
    const int rq = tid & 15;                  // row-quad 0..15
    const int cq = tid >> 4;                  // code-oct 0..15
    const int row0 = blockIdx.x * 64 + rq * 4;      // first of 4 rows
    const int code0 = blockIdx.y * 128 + cq * 8;    // first of 8 codes
    const int b = row0 >> 13;
    const int t = row0 & (T_DIM - 1);               // multiple of 4

    const float* zp = z + (size_t)b * (D_DIM * T_DIM) + t;  // + k*8192
    const float* wp = wT + code0;                           // + k*1024

    float acc[4][8];
#pragma unroll
    for (int r = 0; r < 4; ++r)
#pragma unroll
        for (int c = 0; c < 8; ++c) acc[r][c] = 0.0f;

#pragma unroll
    for (int k = 0; k < D_DIM; ++k) {
        const float4 z4 = *(const float4*)(zp + (size_t)k * T_DIM);
        const float4 wa = *(const float4*)(wp + (size_t)k * C_DIM);
        const float4 wb = *(const float4*)(wp + (size_t)k * C_DIM + 4);
        const float zr[4] = {z4.x, z4.y, z4.z, z4.w};
        const float wc[8] = {wa.x, wa.y, wa.z, wa.w, wb.x, wb.y, wb.z, wb.w};
#pragma unroll
        for (int r = 0; r < 4; ++r)
#pragma unroll
            for (int c = 0; c < 8; ++c)
                acc[r][c] = fmaf(zr[r], wc[c], acc[r][c]);  // serial in k
    }

    const float4 zs4 = *(const float4*)(zsq + row0);
    const float4 wsa = *(const float4*)(wsq + code0);
    const float4 wsb = *(const float4*)(wsq + code0 + 4);
    const float zs[4] = {zs4.x, zs4.y, zs4.z, zs4.w};
    const float wsv[8] = {wsa.x, wsa.y, wsa.z, wsa.w,
                          wsb.x, wsb.y, wsb.z, wsb.w};

    // Per-thread first-min over 8 codes (ascending c, strict <), per row.
    // RSTRIDE pads LDS to 36,864 B: occupancy governor (see header comment).
    __shared__ float2 red[16 * RSTRIDE];
#pragma unroll
    for (int r = 0; r < 4; ++r) {
        float bestd = 3.4e38f;
        int besti = 0;
#pragma unroll
        for (int c = 0; c < 8; ++c) {
            // d = (zsq - 2*dot) + wsq, each op individually rounded
            float d = __fadd_rn(__fsub_rn(zs[r], __fmul_rn(2.0f, acc[r][c])),
                                wsv[c]);
            if (d < bestd) { bestd = d; besti = code0 + c; }
        }
        red[cq * RSTRIDE + rq * 4 + r] = make_float2(bestd, (float)besti);
    }
    __syncthreads();

    // First wave reduces over the 16 code-octs (ascending -> first-min).
    if (tid < 64) {
        float2 best = red[tid];
#pragma unroll
        for (int c = 1; c < 16; ++c) {
            float2 p = red[c * RSTRIDE + tid];
            if (p.x < best.x) best = p;
        }
        pairs[blockIdx.y * NROWS + blockIdx.x * 64 + tid] = best;
    }
}

__global__ void vq_argmin_kernel(const float2* __restrict__ pairs,
                                 float* __restrict__ codes) {
    int row = blockIdx.x * blockDim.x + threadIdx.x;
    float2 best = pairs[row];
#pragma unroll
    for (int s = 1; s < SEGS; ++s) {
        float2 p = pairs[s * NROWS + row];
        if (p.x < best.x) best = p;  // ascending seg order, strict <
    }
    codes[row] = best.y;
}

// One float4 (4 consecutive t) per thread; per-block double partial to ws.
__global__ void vq_epilogue_kernel(const float* __restrict__ z,
                                   const float* __restrict__ cb,
                                   const float* __restrict__ codes,
                                   float* __restrict__ out,
                                   double* __restrict__ partials) {
    const int q = blockIdx.x * 256 + threadIdx.x;  // quad index, 0..1048575
    const int i = q << 2;                          // element index
    const int t = i & (T_DIM - 1);                 // multiple of 4
    const int bd = i >> 13;
    const int d = bd & (D_DIM - 1);                // uniform within a wave
    const int b = bd >> 6;
    const int row = (b << 13) | t;

    float4 cr = *(const float4*)(codes + row);     // 4 consecutive codes
    float4 zv = *(const float4*)(z + i);
    float w0 = cb[((int)cr.x << 6) + d];           // gathers, 256 KiB table
    float w1 = cb[((int)cr.y << 6) + d];
    float w2 = cb[((int)cr.z << 6) + d];
    float w3 = cb[((int)cr.w << 6) + d];

    float4 df = make_float4(w0 - zv.x, w1 - zv.y, w2 - zv.z, w3 - zv.w);
    float4 o = make_float4(zv.x + df.x, zv.y + df.y, zv.z + df.z, zv.w + df.w);
    *(float4*)(out + i) = o;                       // z + (z_q - z), ref order

    double v = (double)df.x * df.x + (double)df.y * df.y +
               (double)df.z * df.z + (double)df.w * df.w;
#pragma unroll
    for (int o2 = 32; o2 > 0; o2 >>= 1) v += __shfl_down(v, o2, 64);

    __shared__ double red[4];
    if ((threadIdx.x & 63) == 0) red[threadIdx.x >> 6] = v;
    __syncthreads();
    if (threadIdx.x == 0)
        partials[blockIdx.x] = ((red[0] + red[1]) + (red[2] + red[3]));
}

__global__ void vq_loss_kernel(const double* __restrict__ partials,
                               float* __restrict__ out_loss) {
    double s = 0.0;
    for (int i = threadIdx.x; i < EPI_BLOCKS; i += 256) s += partials[i];
#pragma unroll
    for (int o = 32; o > 0; o >>= 1) s += __shfl_down(s, o, 64);
    __shared__ double red[4];
    if ((threadIdx.x & 63) == 0) red[threadIdx.x >> 6] = s;
    __syncthreads();
    if (threadIdx.x == 0) {
        double tot = (red[0] + red[1]) + (red[2] + red[3]);
        // vq_loss = codebook_loss + 0.25*commitment_loss = 1.25*mean(diff^2)
        out_loss[0] = (float)(1.25 * tot / (double)NELEM);
    }
}

extern "C" void kernel_launch(void* const* d_in, const int* in_sizes, int n_in,
                              void* d_out, int out_size, void* d_ws, size_t ws_size,
                              hipStream_t stream) {
    const float* z  = (const float*)d_in[0];   // 4194304
    const float* cb = (const float*)d_in[1];   // 65536

    float* out      = (float*)d_out;
    float* out_loss = out + NELEM;             // index 4194304
    float* codes    = out + NELEM + 1;         // 65536 floats

    char* ws = (char*)d_ws;
    float* wT        = (float*)ws;                        // 256 KiB [k][c]
    float* wsq       = (float*)(ws + 262144);             // 4 KiB
    float* zsq       = (float*)(ws + 262144 + 4096);      // 256 KiB
    double* partials = (double*)(ws + 524288 + 4096);     // 32 KiB
    float2* pairs    = (float2*)(ws + 524288 + 4096 + 32768);  // 4 MiB

    vq_prep_kernel<<<C_DIM / 64, 64, 0, stream>>>(cb, wT, wsq);

    vq_zsq_kernel<<<NROWS / 256, 256, 0, stream>>>(z, zsq);

    dim3 grid1(NROWS / 64, SEGS);
    vq_gemm_kernel<<<grid1, 256, 0, stream>>>(z, wT, zsq, wsq, pairs);

    vq_argmin_kernel<<<NROWS / 256, 256, 0, stream>>>(pairs, codes);

    vq_epilogue_kernel<<<EPI_BLOCKS, 256, 0, stream>>>(z, cb, codes, out, partials);

    vq_loss_kernel<<<1, 256, 0, stream>>>(partials, out_loss);
}